// Round 17
// baseline (129.680 us; speedup 1.0000x reference)
//
#include <hip/hip_runtime.h>
#include <hip/hip_bf16.h>
#include <math.h>

#define N_FEAT 6272
#define DIM    128
#define M_BANK 30000
#define M_PAD  30080
#define NB     8
#define PH     28
#define PW     28
#define IMG    224
#define BM     256        // 4 waves x 64 rows (4 mb-blocks of 16)
#define BN     128        // bank cols per tile (16KB fp8)
#define TPT    5          // tiles per chunk: 235 / 47
#define CHUNKS 47
#define TILE_BYTES 16384  // 128 cols x 128 k x 1B

#define BANKQ_BLOCKS (M_PAD / 64)    // 470
#define FEATQ_BLOCKS (N_FEAT / 64)   // 98

typedef __attribute__((ext_vector_type(4)))  int    i32x4;
typedef __attribute__((ext_vector_type(8)))  int    i32x8;
typedef __attribute__((ext_vector_type(4)))  float  f32x4;
typedef __attribute__((ext_vector_type(2)))  float  f32x2;

typedef const __attribute__((address_space(1))) unsigned int g_u32;
typedef __attribute__((address_space(3))) unsigned int l_u32;

// Quantize 32 floats -> 8 dwords of fp8 e4m3 (OCP, RNE, satfinite).
static __device__ __forceinline__ void q32(const float* x, i32x4& q0, i32x4& q1) {
    #pragma unroll
    for (int d = 0; d < 4; ++d) {
        int t = __builtin_amdgcn_cvt_pk_fp8_f32(x[d*4+0], x[d*4+1], 0, false);
        t     = __builtin_amdgcn_cvt_pk_fp8_f32(x[d*4+2], x[d*4+3], t, true);
        q0[d] = t;
    }
    #pragma unroll
    for (int d = 0; d < 4; ++d) {
        int t = __builtin_amdgcn_cvt_pk_fp8_f32(x[16+d*4+0], x[16+d*4+1], 0, false);
        t     = __builtin_amdgcn_cvt_pk_fp8_f32(x[16+d*4+2], x[16+d*4+3], t, true);
        q1[d] = t;
    }
}

// Fused prep. Bank blocks: fp8-quantize + retile into B-fragment order:
// tile t (128 cols, 16KB) | kq-slice s (4 x 4KB) | half (2 x 2KB) | col*16.
// m2h = -(|m|^2+1024)/2 as the MFMA C operand (pad rows: -1e30, not -inf:
// the packed-code OR would turn -inf into NaN). Feature blocks: row-major
// fp8 + nn64 init.
__global__ __launch_bounds__(256) void prep_all(const float* __restrict__ bank,
                                                const float* __restrict__ feat,
                                                unsigned char* __restrict__ mbq,
                                                unsigned char* __restrict__ fbq,
                                                float* __restrict__ m2h,
                                                unsigned long long* __restrict__ nn64) {
    const int tid = threadIdx.x;
    const int c   = tid >> 2;     // row within 64-row block
    const int s   = tid & 3;      // 32-elem k slice
    float x[32];
    if (blockIdx.x < BANKQ_BLOCKS) {
        const int r = blockIdx.x * 64 + c;
        const bool valid = r < M_BANK;
        if (valid) {
            #pragma unroll
            for (int i = 0; i < 8; ++i) {
                f32x4 v = *(const f32x4*)(bank + (size_t)r * DIM + s * 32 + i * 4);
                x[i*4+0]=v.x; x[i*4+1]=v.y; x[i*4+2]=v.z; x[i*4+3]=v.w;
            }
        } else {
            #pragma unroll
            for (int i = 0; i < 32; ++i) x[i] = 0.f;
        }
        float sum = 0.f;
        #pragma unroll
        for (int i = 0; i < 32; ++i) sum += x[i] * x[i];
        sum += __shfl_xor(sum, 1);
        sum += __shfl_xor(sum, 2);
        i32x4 q0, q1;
        q32(x, q0, q1);
        unsigned char* base = mbq + (size_t)(r >> 7) * TILE_BYTES + s * 4096 + (r & 127) * 16;
        *(i32x4*)(base)        = q0;   // k elems 0-15 of slice
        *(i32x4*)(base + 2048) = q1;   // k elems 16-31
        if (s == 0) m2h[r] = valid ? (-0.5f * (sum + 1024.0f)) : -1e30f;
        return;
    }
    const int r = (blockIdx.x - BANKQ_BLOCKS) * 64 + c;   // exact: 98*64 = 6272
    #pragma unroll
    for (int i = 0; i < 8; ++i) {
        f32x4 v = *(const f32x4*)(feat + (size_t)r * DIM + s * 32 + i * 4);
        x[i*4+0]=v.x; x[i*4+1]=v.y; x[i*4+2]=v.z; x[i*4+3]=v.w;
    }
    i32x4 q0, q1;
    q32(x, q0, q1);
    *(i32x4*)(fbq + (size_t)r * DIM + s * 32)      = q0;
    *(i32x4*)(fbq + (size_t)r * DIM + s * 32 + 16) = q1;
    if (s == 0) nn64[r] = 0xFFFFFFFFFFFFFFFFull;
}

// fp8 K=128 argmin, r16 structure with BN=128 tiles: 5 barriers/chunk
// instead of 10 -- per-tile fixed costs (barrier convoy, loop control, m2
// swap) amortize over 2x compute. Packed-code fold (2 VALU/acc): p =
// (bits(acc) & ~1023) | ((t*8+n)<<4 | c16), then v_max_f32. setprio(1)
// around the MFMA cluster (T5; cross-block phase diversity exists).
__global__ __launch_bounds__(256, 4) void dist_min_kernel(
        const unsigned char* __restrict__ fbq, const unsigned char* __restrict__ mbq,
        const float* __restrict__ m2h, unsigned long long* __restrict__ nn64) {
    __shared__ __align__(16) unsigned char lds[2 * TILE_BYTES];
    const int tid  = threadIdx.x;
    const int lane = tid & 63;
    const int w    = tid >> 6;
    const int c16  = lane & 15;   // A-row16 / B-col16 / C-col
    const int kq   = lane >> 4;   // k-quarter (32 elems each)
    const int arow = blockIdx.x * BM + w * 64;
    const int tile0 = blockIdx.y * TPT;

    // A fragments: afrag[mb] = A[arow+mb*16+c16][kq*32 .. +31], two dwordx4
    // part-writes into one i32x8 (adjacent regs, no repack movs).
    i32x8 afrag[4];
    #pragma unroll
    for (int mb = 0; mb < 4; ++mb) {
        int row = arow + mb * 16 + c16;
        if (row >= N_FEAT) row = N_FEAT - 1;   // tail clamp (discarded)
        ((i32x4*)&afrag[mb])[0] = *(const i32x4*)(fbq + (size_t)row * DIM + kq * 32);
        ((i32x4*)&afrag[mb])[1] = *(const i32x4*)(fbq + (size_t)row * DIM + kq * 32 + 16);
    }

    float maxp[4][4];
    #pragma unroll
    for (int mb = 0; mb < 4; ++mb)
        #pragma unroll
        for (int j = 0; j < 4; ++j) maxp[mb][j] = -INFINITY;

#define STAGE(tile_idx, bufsel)                                                      \
    {   const unsigned char* sp_ = mbq + (size_t)(tile_idx) * TILE_BYTES + tid * 16; \
        unsigned char* dp_ = lds + (bufsel) * TILE_BYTES + tid * 16;                 \
        _Pragma("unroll")                                                            \
        for (int i_ = 0; i_ < 4; ++i_)                                               \
            __builtin_amdgcn_global_load_lds((g_u32*)(sp_ + i_ * 4096),              \
                                             (l_u32*)(dp_ + i_ * 4096), 16, 0, 0); }

    // prologue: m2h for tile0 (before STAGE: vmcnt-FIFO discipline), stage.
    float m2c[8];
    #pragma unroll
    for (int n = 0; n < 8; ++n) m2c[n] = m2h[tile0 * BN + n * 16 + c16];
    STAGE(tile0, 0);
    __syncthreads();

    int cur = 0;
    #pragma unroll 1
    for (int t = 0; t < TPT; ++t) {
        float m2n[8];
        if (t + 1 < TPT) {
            #pragma unroll
            for (int n = 0; n < 8; ++n)
                m2n[n] = m2h[(tile0 + t + 1) * BN + n * 16 + c16];
            STAGE(tile0 + t + 1, cur ^ 1);
        }
        const unsigned char* buf = lds + cur * TILE_BYTES;
        #pragma unroll
        for (int n = 0; n < 8; ++n) {
            const int col = n * 16 + c16;
            i32x8 bfrag;
            ((i32x4*)&bfrag)[0] = *(const i32x4*)(buf + kq * 4096 + col * 16);
            ((i32x4*)&bfrag)[1] = *(const i32x4*)(buf + kq * 4096 + 2048 + col * 16);
            const f32x4 cin = {m2c[n], m2c[n], m2c[n], m2c[n]};
            const unsigned int code = (unsigned int)(((t * 8 + n) << 4) | c16);
            f32x4 acc[4];
            __builtin_amdgcn_s_setprio(1);
            #pragma unroll
            for (int mb = 0; mb < 4; ++mb)
                acc[mb] = __builtin_amdgcn_mfma_scale_f32_16x16x128_f8f6f4(
                    afrag[mb], bfrag, cin, 0, 0, 0, 127, 0, 127);
            __builtin_amdgcn_s_setprio(0);
            #pragma unroll
            for (int mb = 0; mb < 4; ++mb)
                #pragma unroll
                for (int j = 0; j < 4; ++j) {
                    unsigned int p = (__float_as_uint(acc[mb][j]) & 0xFFFFFC00u) | code;
                    maxp[mb][j] = fmaxf(maxp[mb][j], __uint_as_float(p));
                }
        }
        __syncthreads();
        if (t + 1 < TPT) {
            #pragma unroll
            for (int n = 0; n < 8; ++n) m2c[n] = m2n[n];
        }
        cur ^= 1;
    }
#undef STAGE

    // Epilogue: pure fmax reduce across the 16 col-lanes (same kq), decode
    // (t, n, c16) from the winner's low 10 bits, one u64 atomic per row.
    #pragma unroll
    for (int mb = 0; mb < 4; ++mb)
        #pragma unroll
        for (int j = 0; j < 4; ++j) {
            float v = maxp[mb][j];
            v = fmaxf(v, __shfl_xor(v, 1));
            v = fmaxf(v, __shfl_xor(v, 2));
            v = fmaxf(v, __shfl_xor(v, 4));
            v = fmaxf(v, __shfl_xor(v, 8));
            if (c16 == 0) {
                int row = arow + mb * 16 + kq * 4 + j;
                if (row < N_FEAT) {
                    unsigned int bits = __float_as_uint(v);
                    unsigned int code = bits & 1023u;
                    unsigned int tn = code >> 4;
                    unsigned int col = (unsigned int)(tile0 + (tn >> 3)) * BN
                                       + (tn & 7u) * 16 + (code & 15u);
                    // -v > 0 (acc always negative): monotone uint pack.
                    unsigned long long pack =
                        ((unsigned long long)__float_as_uint(-v) << 32) | col;
                    atomicMin(nn64 + row, pack);
                }
            }
        }
}

// Exact fp32 distance for the selected neighbor: one wave per row.
__global__ __launch_bounds__(256) void rescue_kernel(const float* __restrict__ feat,
                                                     const float* __restrict__ bank,
                                                     const unsigned long long* __restrict__ nn64,
                                                     float* __restrict__ nnf) {
    const int row  = blockIdx.x * 4 + (threadIdx.x >> 6);   // 1568*4 = 6272 exact
    const int lane = threadIdx.x & 63;
    const unsigned int idx = (unsigned int)(nn64[row] & 0xFFFFFFFFull);
    f32x2 f = *(const f32x2*)(feat + (size_t)row * DIM + lane * 2);
    f32x2 m = *(const f32x2*)(bank + (size_t)idx * DIM + lane * 2);
    float dx = f.x - m.x, dy = f.y - m.y;
    float d = dx * dx + dy * dy;
    #pragma unroll
    for (int k = 1; k < 64; k <<= 1) d += __shfl_xor(d, k);
    if (lane == 0) nnf[row] = d;
}

// Merged finalize: blocks 0..UP_BLOCKS-1 bilinear upsample; last NB blocks
// per-image max.
#define UP_BLOCKS ((NB * IMG * IMG) / 256)   // 1568
__global__ __launch_bounds__(256) void finalize_kernel(const float* __restrict__ nnf,
                                                       float* __restrict__ out_scores,
                                                       float* __restrict__ out_up) {
    if (blockIdx.x >= UP_BLOCKS) {
        __shared__ float wmax[4];
        int b = blockIdx.x - UP_BLOCKS;
        int tid = threadIdx.x;
        float v = -INFINITY;
        for (int i = tid; i < PH * PW; i += 256)
            v = fmaxf(v, nnf[b * PH * PW + i]);
        #pragma unroll
        for (int m = 1; m < 64; m <<= 1) v = fmaxf(v, __shfl_xor(v, m));
        if ((tid & 63) == 0) wmax[tid >> 6] = v;
        __syncthreads();
        if (tid == 0)
            out_scores[b] = fmaxf(fmaxf(wmax[0], wmax[1]), fmaxf(wmax[2], wmax[3]));
        return;
    }
    int idx = blockIdx.x * 256 + threadIdx.x;
    int b = idx / (IMG * IMG);
    int rem = idx - b * (IMG * IMG);
    int y = rem / IMG;
    int x = rem - y * IMG;
    float sy = y * 0.125f - 0.4375f;
    float sx = x * 0.125f - 0.4375f;
    float fy = floorf(sy), fx = floorf(sx);
    float ty = sy - fy, tx = sx - fx;
    int y0 = (int)fy, x0 = (int)fx;
    int y1 = min(y0 + 1, PH - 1), x1 = min(x0 + 1, PW - 1);
    y0 = max(y0, 0); x0 = max(x0, 0);
    const float* p = nnf + b * PH * PW;
    float v00 = p[y0 * PW + x0];
    float v01 = p[y0 * PW + x1];
    float v10 = p[y1 * PW + x0];
    float v11 = p[y1 * PW + x1];
    float v0 = v00 + tx * (v01 - v00);
    float v1 = v10 + tx * (v11 - v10);
    out_up[idx] = v0 + ty * (v1 - v0);
}

extern "C" void kernel_launch(void* const* d_in, const int* in_sizes, int n_in,
                              void* d_out, int out_size, void* d_ws, size_t ws_size,
                              hipStream_t stream) {
    const float* feat = (const float*)d_in[0];   // [6272,128] f32
    const float* bank = (const float*)d_in[1];   // [30000,128] f32
    char* ws = (char*)d_ws;
    unsigned char*      mbq  = (unsigned char*)(ws + 0);        // 30080*128 fp8 tiled = 3,850,240
    unsigned char*      fbq  = (unsigned char*)(ws + 3850240);  // 6272*128 fp8 = 802,816
    float*              m2h  = (float*)(ws + 4653056);          // 30080*4 (= -(m2+1024)/2)
    unsigned long long* nn64 = (unsigned long long*)(ws + 4773376); // 6272*8
    float*              nnf  = (float*)(ws + 4823552);          // 6272*4
    float* out_scores = (float*)d_out;                          // [8]
    float* out_up     = out_scores + NB;                        // [8,224,224]

    hipLaunchKernelGGL(prep_all, dim3(BANKQ_BLOCKS + FEATQ_BLOCKS), dim3(256), 0, stream,
                       bank, feat, mbq, fbq, m2h, nn64);
    hipLaunchKernelGGL(dist_min_kernel, dim3((N_FEAT + BM - 1) / BM, CHUNKS), dim3(256), 0,
                       stream, fbq, mbq, m2h, nn64);
    hipLaunchKernelGGL(rescue_kernel, dim3(N_FEAT / 4), dim3(256), 0, stream,
                       feat, bank, nn64, nnf);
    hipLaunchKernelGGL(finalize_kernel, dim3(UP_BLOCKS + NB), dim3(256), 0, stream,
                       nnf, out_scores, out_up);
}

// Round 18
// 51.739 us; speedup vs baseline: 2.5064x; 2.5064x over previous
//
#include <hip/hip_runtime.h>
#include <hip/hip_bf16.h>
#include <math.h>

#define N_FEAT 6272
#define DIM    128
#define M_BANK 30000
#define M_PAD  30080
#define NB     8
#define PH     28
#define PW     28
#define IMG    224
#define BM     256        // 4 waves x 64 rows (4 mb-blocks of 16)
#define BN     128        // bank cols per tile (16KB fp8)
#define TPT    5          // tiles per chunk: 235 / 47
#define CHUNKS 47
#define TILE_BYTES 16384  // 128 cols x 128 k x 1B

#define BANKQ_BLOCKS (M_PAD / 64)    // 470
#define FEATQ_BLOCKS (N_FEAT / 64)   // 98

typedef __attribute__((ext_vector_type(4)))  int    i32x4;
typedef __attribute__((ext_vector_type(8)))  int    i32x8;
typedef __attribute__((ext_vector_type(4)))  float  f32x4;
typedef __attribute__((ext_vector_type(2)))  float  f32x2;

typedef const __attribute__((address_space(1))) unsigned int g_u32;
typedef __attribute__((address_space(3))) unsigned int l_u32;

// Quantize 32 floats -> 8 dwords of fp8 e4m3 (OCP, RNE, satfinite).
static __device__ __forceinline__ void q32(const float* x, i32x4& q0, i32x4& q1) {
    #pragma unroll
    for (int d = 0; d < 4; ++d) {
        int t = __builtin_amdgcn_cvt_pk_fp8_f32(x[d*4+0], x[d*4+1], 0, false);
        t     = __builtin_amdgcn_cvt_pk_fp8_f32(x[d*4+2], x[d*4+3], t, true);
        q0[d] = t;
    }
    #pragma unroll
    for (int d = 0; d < 4; ++d) {
        int t = __builtin_amdgcn_cvt_pk_fp8_f32(x[16+d*4+0], x[16+d*4+1], 0, false);
        t     = __builtin_amdgcn_cvt_pk_fp8_f32(x[16+d*4+2], x[16+d*4+3], t, true);
        q1[d] = t;
    }
}

// Fused prep. Bank blocks: fp8-quantize + retile into B-fragment order:
// tile t (128 cols, 16KB) | kq-slice s (4 x 4KB) | half (2 x 2KB) | col*16.
// m2h = -(|m|^2+1024)/2 as the MFMA C operand (pad rows: -1e30, not -inf:
// the packed-code OR would turn -inf into NaN). Feature blocks: row-major
// fp8 + nn64 init.
__global__ __launch_bounds__(256) void prep_all(const float* __restrict__ bank,
                                                const float* __restrict__ feat,
                                                unsigned char* __restrict__ mbq,
                                                unsigned char* __restrict__ fbq,
                                                float* __restrict__ m2h,
                                                unsigned long long* __restrict__ nn64) {
    const int tid = threadIdx.x;
    const int c   = tid >> 2;     // row within 64-row block
    const int s   = tid & 3;      // 32-elem k slice
    float x[32];
    if (blockIdx.x < BANKQ_BLOCKS) {
        const int r = blockIdx.x * 64 + c;
        const bool valid = r < M_BANK;
        if (valid) {
            #pragma unroll
            for (int i = 0; i < 8; ++i) {
                f32x4 v = *(const f32x4*)(bank + (size_t)r * DIM + s * 32 + i * 4);
                x[i*4+0]=v.x; x[i*4+1]=v.y; x[i*4+2]=v.z; x[i*4+3]=v.w;
            }
        } else {
            #pragma unroll
            for (int i = 0; i < 32; ++i) x[i] = 0.f;
        }
        float sum = 0.f;
        #pragma unroll
        for (int i = 0; i < 32; ++i) sum += x[i] * x[i];
        sum += __shfl_xor(sum, 1);
        sum += __shfl_xor(sum, 2);
        i32x4 q0, q1;
        q32(x, q0, q1);
        unsigned char* base = mbq + (size_t)(r >> 7) * TILE_BYTES + s * 4096 + (r & 127) * 16;
        *(i32x4*)(base)        = q0;   // k elems 0-15 of slice
        *(i32x4*)(base + 2048) = q1;   // k elems 16-31
        if (s == 0) m2h[r] = valid ? (-0.5f * (sum + 1024.0f)) : -1e30f;
        return;
    }
    const int r = (blockIdx.x - BANKQ_BLOCKS) * 64 + c;   // exact: 98*64 = 6272
    #pragma unroll
    for (int i = 0; i < 8; ++i) {
        f32x4 v = *(const f32x4*)(feat + (size_t)r * DIM + s * 32 + i * 4);
        x[i*4+0]=v.x; x[i*4+1]=v.y; x[i*4+2]=v.z; x[i*4+3]=v.w;
    }
    i32x4 q0, q1;
    q32(x, q0, q1);
    *(i32x4*)(fbq + (size_t)r * DIM + s * 32)      = q0;
    *(i32x4*)(fbq + (size_t)r * DIM + s * 32 + 16) = q1;
    if (s == 0) nn64[r] = 0xFFFFFFFFFFFFFFFFull;
}

// fp8 K=128 argmin, BN=128 tiles (5 barriers/chunk vs r16's 10) with the
// register budget fixed: launch_bounds(256,3) (~170-reg cap) + n-loop
// unroll 4 (caps in-flight bfrag regs at ~32). Packed-code fold
// (2 VALU/acc); setprio(1) around the MFMA cluster.
__global__ __launch_bounds__(256, 3) void dist_min_kernel(
        const unsigned char* __restrict__ fbq, const unsigned char* __restrict__ mbq,
        const float* __restrict__ m2h, unsigned long long* __restrict__ nn64) {
    __shared__ __align__(16) unsigned char lds[2 * TILE_BYTES];
    const int tid  = threadIdx.x;
    const int lane = tid & 63;
    const int w    = tid >> 6;
    const int c16  = lane & 15;   // A-row16 / B-col16 / C-col
    const int kq   = lane >> 4;   // k-quarter (32 elems each)
    const int arow = blockIdx.x * BM + w * 64;
    const int tile0 = blockIdx.y * TPT;

    // A fragments: afrag[mb] = A[arow+mb*16+c16][kq*32 .. +31], two dwordx4
    // part-writes into one i32x8 (adjacent regs, no repack movs).
    i32x8 afrag[4];
    #pragma unroll
    for (int mb = 0; mb < 4; ++mb) {
        int row = arow + mb * 16 + c16;
        if (row >= N_FEAT) row = N_FEAT - 1;   // tail clamp (discarded)
        ((i32x4*)&afrag[mb])[0] = *(const i32x4*)(fbq + (size_t)row * DIM + kq * 32);
        ((i32x4*)&afrag[mb])[1] = *(const i32x4*)(fbq + (size_t)row * DIM + kq * 32 + 16);
    }

    float maxp[4][4];
    #pragma unroll
    for (int mb = 0; mb < 4; ++mb)
        #pragma unroll
        for (int j = 0; j < 4; ++j) maxp[mb][j] = -INFINITY;

#define STAGE(tile_idx, bufsel)                                                      \
    {   const unsigned char* sp_ = mbq + (size_t)(tile_idx) * TILE_BYTES + tid * 16; \
        unsigned char* dp_ = lds + (bufsel) * TILE_BYTES + tid * 16;                 \
        _Pragma("unroll")                                                            \
        for (int i_ = 0; i_ < 4; ++i_)                                               \
            __builtin_amdgcn_global_load_lds((g_u32*)(sp_ + i_ * 4096),              \
                                             (l_u32*)(dp_ + i_ * 4096), 16, 0, 0); }

    // prologue: m2h for tile0 (before STAGE: vmcnt-FIFO discipline), stage.
    float m2c[8];
    #pragma unroll
    for (int n = 0; n < 8; ++n) m2c[n] = m2h[tile0 * BN + n * 16 + c16];
    STAGE(tile0, 0);
    __syncthreads();

    int cur = 0;
    #pragma unroll 1
    for (int t = 0; t < TPT; ++t) {
        float m2n[8];
        if (t + 1 < TPT) {
            #pragma unroll
            for (int n = 0; n < 8; ++n)
                m2n[n] = m2h[(tile0 + t + 1) * BN + n * 16 + c16];
            STAGE(tile0 + t + 1, cur ^ 1);
        }
        const unsigned char* buf = lds + cur * TILE_BYTES;
        #pragma unroll 4
        for (int n = 0; n < 8; ++n) {
            const int col = n * 16 + c16;
            i32x8 bfrag;
            ((i32x4*)&bfrag)[0] = *(const i32x4*)(buf + kq * 4096 + col * 16);
            ((i32x4*)&bfrag)[1] = *(const i32x4*)(buf + kq * 4096 + 2048 + col * 16);
            const f32x4 cin = {m2c[n], m2c[n], m2c[n], m2c[n]};
            const unsigned int code = (unsigned int)(((t * 8 + n) << 4) | c16);
            f32x4 acc[4];
            __builtin_amdgcn_s_setprio(1);
            #pragma unroll
            for (int mb = 0; mb < 4; ++mb)
                acc[mb] = __builtin_amdgcn_mfma_scale_f32_16x16x128_f8f6f4(
                    afrag[mb], bfrag, cin, 0, 0, 0, 127, 0, 127);
            __builtin_amdgcn_s_setprio(0);
            #pragma unroll
            for (int mb = 0; mb < 4; ++mb)
                #pragma unroll
                for (int j = 0; j < 4; ++j) {
                    unsigned int p = (__float_as_uint(acc[mb][j]) & 0xFFFFFC00u) | code;
                    maxp[mb][j] = fmaxf(maxp[mb][j], __uint_as_float(p));
                }
        }
        __syncthreads();
        if (t + 1 < TPT) {
            #pragma unroll
            for (int n = 0; n < 8; ++n) m2c[n] = m2n[n];
        }
        cur ^= 1;
    }
#undef STAGE

    // Epilogue: pure fmax reduce across the 16 col-lanes (same kq), decode
    // (t, n, c16) from the winner's low 10 bits, one u64 atomic per row.
    #pragma unroll
    for (int mb = 0; mb < 4; ++mb)
        #pragma unroll
        for (int j = 0; j < 4; ++j) {
            float v = maxp[mb][j];
            v = fmaxf(v, __shfl_xor(v, 1));
            v = fmaxf(v, __shfl_xor(v, 2));
            v = fmaxf(v, __shfl_xor(v, 4));
            v = fmaxf(v, __shfl_xor(v, 8));
            if (c16 == 0) {
                int row = arow + mb * 16 + kq * 4 + j;
                if (row < N_FEAT) {
                    unsigned int bits = __float_as_uint(v);
                    unsigned int code = bits & 1023u;
                    unsigned int tn = code >> 4;
                    unsigned int col = (unsigned int)(tile0 + (tn >> 3)) * BN
                                       + (tn & 7u) * 16 + (code & 15u);
                    // -v > 0 (acc always negative): monotone uint pack.
                    unsigned long long pack =
                        ((unsigned long long)__float_as_uint(-v) << 32) | col;
                    atomicMin(nn64 + row, pack);
                }
            }
        }
}

// Exact fp32 distance for the selected neighbor: one wave per row.
__global__ __launch_bounds__(256) void rescue_kernel(const float* __restrict__ feat,
                                                     const float* __restrict__ bank,
                                                     const unsigned long long* __restrict__ nn64,
                                                     float* __restrict__ nnf) {
    const int row  = blockIdx.x * 4 + (threadIdx.x >> 6);   // 1568*4 = 6272 exact
    const int lane = threadIdx.x & 63;
    const unsigned int idx = (unsigned int)(nn64[row] & 0xFFFFFFFFull);
    f32x2 f = *(const f32x2*)(feat + (size_t)row * DIM + lane * 2);
    f32x2 m = *(const f32x2*)(bank + (size_t)idx * DIM + lane * 2);
    float dx = f.x - m.x, dy = f.y - m.y;
    float d = dx * dx + dy * dy;
    #pragma unroll
    for (int k = 1; k < 64; k <<= 1) d += __shfl_xor(d, k);
    if (lane == 0) nnf[row] = d;
}

// Merged finalize: blocks 0..UP_BLOCKS-1 bilinear upsample; last NB blocks
// per-image max.
#define UP_BLOCKS ((NB * IMG * IMG) / 256)   // 1568
__global__ __launch_bounds__(256) void finalize_kernel(const float* __restrict__ nnf,
                                                       float* __restrict__ out_scores,
                                                       float* __restrict__ out_up) {
    if (blockIdx.x >= UP_BLOCKS) {
        __shared__ float wmax[4];
        int b = blockIdx.x - UP_BLOCKS;
        int tid = threadIdx.x;
        float v = -INFINITY;
        for (int i = tid; i < PH * PW; i += 256)
            v = fmaxf(v, nnf[b * PH * PW + i]);
        #pragma unroll
        for (int m = 1; m < 64; m <<= 1) v = fmaxf(v, __shfl_xor(v, m));
        if ((tid & 63) == 0) wmax[tid >> 6] = v;
        __syncthreads();
        if (tid == 0)
            out_scores[b] = fmaxf(fmaxf(wmax[0], wmax[1]), fmaxf(wmax[2], wmax[3]));
        return;
    }
    int idx = blockIdx.x * 256 + threadIdx.x;
    int b = idx / (IMG * IMG);
    int rem = idx - b * (IMG * IMG);
    int y = rem / IMG;
    int x = rem - y * IMG;
    float sy = y * 0.125f - 0.4375f;
    float sx = x * 0.125f - 0.4375f;
    float fy = floorf(sy), fx = floorf(sx);
    float ty = sy - fy, tx = sx - fx;
    int y0 = (int)fy, x0 = (int)fx;
    int y1 = min(y0 + 1, PH - 1), x1 = min(x0 + 1, PW - 1);
    y0 = max(y0, 0); x0 = max(x0, 0);
    const float* p = nnf + b * PH * PW;
    float v00 = p[y0 * PW + x0];
    float v01 = p[y0 * PW + x1];
    float v10 = p[y1 * PW + x0];
    float v11 = p[y1 * PW + x1];
    float v0 = v00 + tx * (v01 - v00);
    float v1 = v10 + tx * (v11 - v10);
    out_up[idx] = v0 + ty * (v1 - v0);
}

extern "C" void kernel_launch(void* const* d_in, const int* in_sizes, int n_in,
                              void* d_out, int out_size, void* d_ws, size_t ws_size,
                              hipStream_t stream) {
    const float* feat = (const float*)d_in[0];   // [6272,128] f32
    const float* bank = (const float*)d_in[1];   // [30000,128] f32
    char* ws = (char*)d_ws;
    unsigned char*      mbq  = (unsigned char*)(ws + 0);        // 30080*128 fp8 tiled = 3,850,240
    unsigned char*      fbq  = (unsigned char*)(ws + 3850240);  // 6272*128 fp8 = 802,816
    float*              m2h  = (float*)(ws + 4653056);          // 30080*4 (= -(m2+1024)/2)
    unsigned long long* nn64 = (unsigned long long*)(ws + 4773376); // 6272*8
    float*              nnf  = (float*)(ws + 4823552);          // 6272*4
    float* out_scores = (float*)d_out;                          // [8]
    float* out_up     = out_scores + NB;                        // [8,224,224]

    hipLaunchKernelGGL(prep_all, dim3(BANKQ_BLOCKS + FEATQ_BLOCKS), dim3(256), 0, stream,
                       bank, feat, mbq, fbq, m2h, nn64);
    hipLaunchKernelGGL(dist_min_kernel, dim3((N_FEAT + BM - 1) / BM, CHUNKS), dim3(256), 0,
                       stream, fbq, mbq, m2h, nn64);
    hipLaunchKernelGGL(rescue_kernel, dim3(N_FEAT / 4), dim3(256), 0, stream,
                       feat, bank, nn64, nnf);
    hipLaunchKernelGGL(finalize_kernel, dim3(UP_BLOCKS + NB), dim3(256), 0, stream,
                       nnf, out_scores, out_up);
}